// Round 6
// baseline (361.412 us; speedup 1.0000x reference)
//
#include <hip/hip_runtime.h>
#include <math.h>

#define NB   256
#define PTS  512
#define EMB  12
#define NHD  4

typedef short short8v __attribute__((ext_vector_type(8)));
typedef float floatx4 __attribute__((ext_vector_type(4)));

union U16 { uint4 u; short8v s; };

// float -> bf16 bits (round to nearest even), low 16 of return
__device__ __forceinline__ unsigned bf16rne(float x) {
  union { float f; unsigned u; } v; v.f = x;
  return (v.u + 0x7FFFu + ((v.u >> 16) & 1u)) >> 16;
}
// pack two floats as bf16 pair (truncation): low short = bf16(a), high = bf16(b)
__device__ __forceinline__ unsigned packbf(float a, float b) {
  return (__float_as_uint(a) >> 16) | (__float_as_uint(b) & 0xFFFF0000u);
}
// clamped exp2 — clamp is inert for correct data (|s| <~ 5) but prevents inf
__device__ __forceinline__ float cexp2(float s) {
  return exp2f(fminf(fmaxf(s, -30.f), 30.f));
}

// ---------------- block-wide reduction of N floats (512 threads = 8 waves) ----------------
template<int N>
__device__ __forceinline__ void block_reduce(float* v, float* sred, int t) {
  const int lane = t & 63;
  const int wv   = t >> 6;
  #pragma unroll
  for (int i = 0; i < N; ++i) {
    float s = v[i];
    #pragma unroll
    for (int off = 32; off > 0; off >>= 1) s += __shfl_down(s, off, 64);
    if (lane == 0) sred[wv * N + i] = s;
  }
  __syncthreads();
  #pragma unroll
  for (int i = 0; i < N; ++i) {
    float s = 0.f;
    #pragma unroll
    for (int w = 0; w < 8; ++w) s += sred[w * N + i];
    v[i] = s;
  }
  __syncthreads();
}

// ---------------- one MHA layer via verified mfma_f32_16x16x32_bf16 ----------------
// Sᵀ = K·Qᵀ:  A = K-tile (lane m=ln is key; slots j=0..2 = k0,k1,k2, rest 0, dup all quads)
//             B = Qᵀ     (lane n=ln is qrow; quad 0 slots 0..2 = q0,q1,q2; quads>=1 zeroed)
//   D (C-layout): lane ln,quad lq, reg r -> Sᵀ[key=4*lq+r][qrow=ln]
// PV over 32 keys (tiles 2g, 2g+1): A slot (lq,j) carries key (j<4 ? 4lq+j : 16+4lq+j-4);
// V staged (svB) with the SAME (lq,j)->key formula, so exp(Sᵀ) feeds PV from registers.
// V column 3 = ones -> softmax denominator.
__device__ __forceinline__ void mha_mfma(
    const float* qin, const float* kvin,
    const float* __restrict__ w_in, const float* __restrict__ b_in,
    const float* __restrict__ w_out, const float* __restrict__ b_out,
    float* outv,
    uint4* skA, uint4* sqQ, unsigned short* svB, float* sO, int t)
{
  __syncthreads();   // previous layer's consumers of all LDS regions are done

  // ---- stage: project this thread's row to q,k,v; write bf16 fragments ----
  {
    const float qs = 0.5773502691896258f * 1.4426950408889634f; // 1/sqrt(3)*log2(e)
    float kk[EMB], vv[EMB], qq[EMB];
    #pragma unroll
    for (int e = 0; e < EMB; ++e) {
      float q_ = b_in[e], k_ = b_in[EMB + e], v_ = b_in[2 * EMB + e];
      #pragma unroll
      for (int f = 0; f < EMB; ++f) {
        q_ = fmaf(qin[f],  w_in[e * EMB + f],             q_);
        k_ = fmaf(kvin[f], w_in[(EMB + e) * EMB + f],     k_);
        v_ = fmaf(kvin[f], w_in[(2 * EMB + e) * EMB + f], v_);
      }
      qq[e] = q_ * qs; kk[e] = k_; vv[e] = v_;
    }
    const int kt = t >> 4, kap = t & 15;          // key-tile, key-within-tile
    const int grp = t >> 5, g = t & 31;           // 32-key PV group
    const int odd = g >> 4, sub = g & 15;
    const int q4 = sub >> 2, jj = (sub & 3) + 4 * odd;
    #pragma unroll
    for (int h = 0; h < NHD; ++h) {
      skA[(kt * NHD + h) * 16 + kap] =
          make_uint4(bf16rne(kk[h*3]) | (bf16rne(kk[h*3+1]) << 16), bf16rne(kk[h*3+2]), 0u, 0u);
      sqQ[(kt * NHD + h) * 16 + kap] =
          make_uint4(bf16rne(qq[h*3]) | (bf16rne(qq[h*3+1]) << 16), bf16rne(qq[h*3+2]), 0u, 0u);
      #pragma unroll
      for (int n = 0; n < 4; ++n) {
        float vval = (n < 3) ? vv[h*3+n] : 1.0f;   // ones column -> denom
        svB[(((grp * NHD + h) * 4 + q4) * 4 + n) * 8 + jj] = (unsigned short)bf16rne(vval);
      }
    }
  }
  __syncthreads();

  const int lane = t & 63, wv = t >> 6;
  const int lq = lane >> 4, ln = lane & 15;

  // ---- Qᵀ fragments for this wave's 4 row-tiles (quads >= 1 zeroed) ----
  short8v qf[4][NHD];
  #pragma unroll
  for (int i = 0; i < 4; ++i)
    #pragma unroll
    for (int h = 0; h < NHD; ++h) {
      U16 u; u.u = sqQ[((wv * 4 + i) * NHD + h) * 16 + ln];
      if (lq != 0) u.u = make_uint4(0u, 0u, 0u, 0u);
      qf[i][h] = u.s;
    }

  floatx4 oacc[4][NHD];
  #pragma unroll
  for (int i = 0; i < 4; ++i)
    #pragma unroll
    for (int h = 0; h < NHD; ++h) {
      floatx4 z = {0.f, 0.f, 0.f, 0.f};
      oacc[i][h] = z;
    }

  const uint4* svB4 = (const uint4*)svB;
  for (int kg = 0; kg < 16; ++kg) {
    #pragma unroll
    for (int h = 0; h < NHD; ++h) {
      U16 ke, ko, vf;
      ke.u = skA[((2 * kg + 0) * NHD + h) * 16 + ln];            // even key-tile (bcast x4)
      ko.u = skA[((2 * kg + 1) * NHD + h) * 16 + ln];            // odd key-tile
      vf.u = svB4[((kg * NHD + h) * 4 + lq) * 4 + (ln & 3)];     // V' frag (permuted order)
      #pragma unroll
      for (int i = 0; i < 4; ++i) {
        floatx4 zc = {0.f, 0.f, 0.f, 0.f};
        floatx4 se = __builtin_amdgcn_mfma_f32_16x16x32_bf16(ke.s, qf[i][h], zc, 0, 0, 0);
        floatx4 so = __builtin_amdgcn_mfma_f32_16x16x32_bf16(ko.s, qf[i][h], zc, 0, 0, 0);
        float p0 = cexp2(se[0]), p1 = cexp2(se[1]);
        float p2 = cexp2(se[2]), p3 = cexp2(se[3]);
        float p4 = cexp2(so[0]), p5 = cexp2(so[1]);
        float p6 = cexp2(so[2]), p7 = cexp2(so[3]);
        U16 pf;
        pf.u.x = packbf(p0, p1);   // slots j=0,1
        pf.u.y = packbf(p2, p3);   // slots j=2,3
        pf.u.z = packbf(p4, p5);   // slots j=4,5
        pf.u.w = packbf(p6, p7);   // slots j=6,7
        oacc[i][h] = __builtin_amdgcn_mfma_f32_16x16x32_bf16(pf.s, vf.s, oacc[i][h], 0, 0, 0);
      }
    }
  }

  // ---- redistribute O (C-layout, cols 0..3 valid) to per-row layout in LDS ----
  if (ln < 4) {
    #pragma unroll
    for (int i = 0; i < 4; ++i)
      #pragma unroll
      for (int h = 0; h < NHD; ++h)
        #pragma unroll
        for (int r = 0; r < 4; ++r)
          sO[((wv * 4 + i) * 16 + lq * 4 + r) * 16 + h * 4 + ln] = oacc[i][h][r];
  }
  __syncthreads();

  // ---- normalize + out-projection for this thread's row ----
  {
    const float4* sr = (const float4*)(sO + t * 16);
    float o[EMB];
    #pragma unroll
    for (int h = 0; h < NHD; ++h) {
      float4 Oh = sr[h];
      float inv = 1.0f / fmaxf(Oh.w, 1e-20f);   // guard: finite even if layout wrong
      o[h*3+0] = Oh.x * inv; o[h*3+1] = Oh.y * inv; o[h*3+2] = Oh.z * inv;
    }
    #pragma unroll
    for (int e = 0; e < EMB; ++e) {
      float s = b_out[e];
      #pragma unroll
      for (int f = 0; f < EMB; ++f) s = fmaf(o[f], w_out[e * EMB + f], s);
      outv[e] = s;
    }
  }
}

__global__ __launch_bounds__(512, 2)
void pcr_kernel(const float* __restrict__ x_orig, const float* __restrict__ y_orig,
                const float* __restrict__ lin_in_w,  const float* __restrict__ lin_in_b,
                const float* __restrict__ lin_in2_w, const float* __restrict__ lin_in2_b,
                const float* __restrict__ attn_in_w,  const float* __restrict__ attn_in_b,
                const float* __restrict__ attn_out_w, const float* __restrict__ attn_out_b,
                const float* __restrict__ attn2_in_w,  const float* __restrict__ attn2_in_b,
                const float* __restrict__ attn2_out_w, const float* __restrict__ attn2_out_b,
                const float* __restrict__ cross_in_w,  const float* __restrict__ cross_in_b,
                const float* __restrict__ cross_out_w, const float* __restrict__ cross_out_b,
                const float* __restrict__ lin_out_w, const float* __restrict__ lin_out_b,
                float* __restrict__ out)
{
  __shared__ __align__(16) uint4 skA[32 * NHD * 16];                   // 32 KB [kt][h][key]
  __shared__ __align__(16) uint4 sqQ[32 * NHD * 16];                   // 32 KB [rt][h][row]
  __shared__ __align__(16) unsigned short svB[16 * NHD * 4 * 4 * 8];   // 16 KB [kg][h][lq][n][j]
  __shared__ __align__(16) float sO[PTS * 16];                         // 32 KB
  __shared__ float sred[8 * 12];

  const int b = blockIdx.x;
  const int t = threadIdx.x;
  const int base = (b * PTS + t) * 3;

  // ---- center x and y (per-batch mean over points) ----
  float x3[3], y3[3], ymean[3];
  {
    float r6[6];
    #pragma unroll
    for (int i = 0; i < 3; ++i) r6[i]     = x_orig[base + i];
    #pragma unroll
    for (int i = 0; i < 3; ++i) r6[3 + i] = y_orig[base + i];
    float xl[3] = {r6[0], r6[1], r6[2]};
    float yl[3] = {r6[3], r6[4], r6[5]};
    block_reduce<6>(r6, sred, t);
    #pragma unroll
    for (int i = 0; i < 3; ++i) {
      x3[i]    = xl[i] - r6[i] * (1.f / PTS);
      ymean[i] = r6[3 + i] * (1.f / PTS);
      y3[i]    = yl[i] - ymean[i];
    }
  }

  // ---- input linears (3 -> 12) ----
  float xi[EMB], yi[EMB];
  #pragma unroll
  for (int e = 0; e < EMB; ++e) {
    float sx = lin_in_b[e], sy = lin_in2_b[e];
    #pragma unroll
    for (int i = 0; i < 3; ++i) {
      sx = fmaf(x3[i], lin_in_w[e * 3 + i], sx);
      sy = fmaf(y3[i], lin_in2_w[e * 3 + i], sy);
    }
    xi[e] = sx; yi[e] = sy;
  }

  // ---- three attention layers (MFMA) ----
  float tmp[EMB];
  mha_mfma(xi, xi, attn_in_w,  attn_in_b,  attn_out_w,  attn_out_b,  tmp, skA, sqQ, svB, sO, t);
  #pragma unroll
  for (int e = 0; e < EMB; ++e) xi[e] = tmp[e];
  mha_mfma(yi, yi, attn2_in_w, attn2_in_b, attn2_out_w, attn2_out_b, tmp, skA, sqQ, svB, sO, t);
  #pragma unroll
  for (int e = 0; e < EMB; ++e) yi[e] = tmp[e];
  mha_mfma(xi, yi, cross_in_w, cross_in_b, cross_out_w, cross_out_b, tmp, skA, sqQ, svB, sO, t);

  // ---- output linear (12 -> 3); bp = coords + x ----
  float bp[3];
  #pragma unroll
  for (int d = 0; d < 3; ++d) {
    float c = lin_out_b[d];
    #pragma unroll
    for (int e = 0; e < EMB; ++e) c = fmaf(tmp[e], lin_out_w[d * EMB + e], c);
    bp[d] = c + x3[d];
  }

  // ---- Kabsch: H[i][j] = sum_p x[p,i]*bp[p,j] (sum_p x = 0), plus sum bp ----
  float r12[12];
  #pragma unroll
  for (int i = 0; i < 3; ++i)
    #pragma unroll
    for (int j = 0; j < 3; ++j) r12[i * 3 + j] = x3[i] * bp[j];
  #pragma unroll
  for (int j = 0; j < 3; ++j) r12[9 + j] = bp[j];
  block_reduce<12>(r12, sred, t);

  float cA[3];
  #pragma unroll
  for (int j = 0; j < 3; ++j) cA[j] = r12[9 + j] * (1.f / PTS);

  // ---- R = polar factor of H via determinant-scaled Newton (== U @ Vt) ----
  float a00 = r12[0], a01 = r12[1], a02 = r12[2];
  float a10 = r12[3], a11 = r12[4], a12_ = r12[5];
  float a20 = r12[6], a21 = r12[7], a22 = r12[8];

  float c0 = fabsf(a00) + fabsf(a10) + fabsf(a20);
  float c1 = fabsf(a01) + fabsf(a11) + fabsf(a21);
  float c2 = fabsf(a02) + fabsf(a12_) + fabsf(a22);
  float r0 = fabsf(a00) + fabsf(a01) + fabsf(a02);
  float r1 = fabsf(a10) + fabsf(a11) + fabsf(a12_);
  float r2 = fabsf(a20) + fabsf(a21) + fabsf(a22);
  float fsc = rsqrtf(fmaxf(c0, fmaxf(c1, c2)) * fmaxf(r0, fmaxf(r1, r2)) + 1e-30f);
  a00 *= fsc; a01 *= fsc; a02 *= fsc;
  a10 *= fsc; a11 *= fsc; a12_ *= fsc;
  a20 *= fsc; a21 *= fsc; a22 *= fsc;

  #pragma unroll 1
  for (int it = 0; it < 12; ++it) {
    float C00 = a11*a22 - a12_*a21;
    float C01 = a12_*a20 - a10*a22;
    float C02 = a10*a21 - a11*a20;
    float C10 = a02*a21 - a01*a22;
    float C11 = a00*a22 - a02*a20;
    float C12 = a01*a20 - a00*a21;
    float C20 = a01*a12_ - a02*a11;
    float C21 = a02*a10 - a00*a12_;
    float C22 = a00*a11 - a01*a10;
    float det = a00*C00 + a01*C01 + a02*C02;
    float g  = 1.0f / cbrtf(fabsf(det) + 1e-30f);
    float dg = det * g;
    dg = copysignf(fmaxf(fabsf(dg), 1e-25f), dg);   // guard: never divide by 0
    float id = 0.5f / dg;
    float gh = 0.5f * g;
    a00 = gh*a00 + C00*id; a01 = gh*a01 + C01*id; a02 = gh*a02 + C02*id;
    a10 = gh*a10 + C10*id; a11 = gh*a11 + C11*id; a12_ = gh*a12_ + C12*id;
    a20 = gh*a20 + C20*id; a21 = gh*a21 + C21*id; a22 = gh*a22 + C22*id;
    // finiteness clamp (inert for correct data: |a| <= ~1)
    a00 = fminf(fmaxf(a00, -1e8f), 1e8f); a01 = fminf(fmaxf(a01, -1e8f), 1e8f);
    a02 = fminf(fmaxf(a02, -1e8f), 1e8f); a10 = fminf(fmaxf(a10, -1e8f), 1e8f);
    a11 = fminf(fmaxf(a11, -1e8f), 1e8f); a12_ = fminf(fmaxf(a12_, -1e8f), 1e8f);
    a20 = fminf(fmaxf(a20, -1e8f), 1e8f); a21 = fminf(fmaxf(a21, -1e8f), 1e8f);
    a22 = fminf(fmaxf(a22, -1e8f), 1e8f);
  }

  // ---- out = x @ R + t + y_translate ----
  float o0 = fmaf(x3[0], a00, fmaf(x3[1], a10, fmaf(x3[2], a20, cA[0] + ymean[0])));
  float o1 = fmaf(x3[0], a01, fmaf(x3[1], a11, fmaf(x3[2], a21, cA[1] + ymean[1])));
  float o2 = fmaf(x3[0], a02, fmaf(x3[1], a12_, fmaf(x3[2], a22, cA[2] + ymean[2])));
  out[base + 0] = o0;
  out[base + 1] = o1;
  out[base + 2] = o2;
}

extern "C" void kernel_launch(void* const* d_in, const int* in_sizes, int n_in,
                              void* d_out, int out_size, void* d_ws, size_t ws_size,
                              hipStream_t stream) {
  const float* p[20];
  for (int i = 0; i < 20; ++i) p[i] = (const float*)d_in[i];
  pcr_kernel<<<dim3(NB), dim3(512), 0, stream>>>(
      p[0], p[1], p[2], p[3], p[4], p[5], p[6], p[7], p[8], p[9],
      p[10], p[11], p[12], p[13], p[14], p[15], p[16], p[17], p[18], p[19],
      (float*)d_out);
}

// Round 7
// 213.045 us; speedup vs baseline: 1.6964x; 1.6964x over previous
//
#include <hip/hip_runtime.h>
#include <math.h>

#define NB   256
#define PTS  512
#define EMB  12
#define NHD  4

typedef short short8v __attribute__((ext_vector_type(8)));
typedef float floatx4 __attribute__((ext_vector_type(4)));

union U16 { uint4 u; short8v s; };

// float -> bf16 bits (round to nearest even), low 16 of return
__device__ __forceinline__ unsigned bf16rne(float x) {
  union { float f; unsigned u; } v; v.f = x;
  return (v.u + 0x7FFFu + ((v.u >> 16) & 1u)) >> 16;
}

// ---------------- block-wide reduction of N floats (512 threads = 8 waves) ----------------
template<int N>
__device__ __forceinline__ void block_reduce(float* v, float* sred, int t) {
  const int lane = t & 63;
  const int wv   = t >> 6;
  #pragma unroll
  for (int i = 0; i < N; ++i) {
    float s = v[i];
    #pragma unroll
    for (int off = 32; off > 0; off >>= 1) s += __shfl_down(s, off, 64);
    if (lane == 0) sred[wv * N + i] = s;
  }
  __syncthreads();
  #pragma unroll
  for (int i = 0; i < N; ++i) {
    float s = 0.f;
    #pragma unroll
    for (int w = 0; w < 8; ++w) s += sred[w * N + i];
    v[i] = s;
  }
  __syncthreads();
}

// ---------------- one MHA layer via verified mfma_f32_16x16x32_bf16 ----------------
// Sᵀ = K·Qᵀ:  A = K-tile (lane m=ln is key; slots j=0..2 = k0,k1,k2, rest 0, dup all quads)
//             B = Qᵀ     (lane n=ln is qrow; quad 0 slots 0..2 = q0,q1,q2; quads>=1 zeroed)
//   D (C-layout): lane ln,quad lq, reg r -> Sᵀ[key=4*lq+r][qrow=ln]
// PV over 32 keys (tiles 2g, 2g+1): A slot (lq,j) carries key (j<4 ? 4lq+j : 16+4lq+j-4);
// V staged (svB) with the SAME (lq,j)->key formula, so exp(Sᵀ) feeds PV from registers.
// V column 3 = ones -> softmax denominator.  [layout end-to-end verified in R6]
__device__ __forceinline__ void mha_mfma(
    const float* qin, const float* kvin,
    const float* __restrict__ w_in, const float* __restrict__ b_in,
    const float* __restrict__ w_out, const float* __restrict__ b_out,
    float* outv,
    uint4* skA, uint4* sqQ, unsigned short* svB, float* sO, int t)
{
  __syncthreads();   // previous layer's consumers of all LDS regions are done

  // ---- stage: project this thread's row to q,k,v; write bf16 fragments ----
  {
    const float qs = 0.5773502691896258f * 1.4426950408889634f; // 1/sqrt(3)*log2(e)
    float kk[EMB], vv[EMB], qq[EMB];
    #pragma unroll
    for (int e = 0; e < EMB; ++e) {
      float q_ = b_in[e], k_ = b_in[EMB + e], v_ = b_in[2 * EMB + e];
      #pragma unroll
      for (int f = 0; f < EMB; ++f) {
        q_ = fmaf(qin[f],  w_in[e * EMB + f],             q_);
        k_ = fmaf(kvin[f], w_in[(EMB + e) * EMB + f],     k_);
        v_ = fmaf(kvin[f], w_in[(2 * EMB + e) * EMB + f], v_);
      }
      qq[e] = q_ * qs; kk[e] = k_; vv[e] = v_;
    }
    const int kt = t >> 4, kap = t & 15;          // key-tile, key-within-tile
    const int grp = t >> 5, g = t & 31;           // 32-key PV group
    const int odd = g >> 4, sub = g & 15;
    const int q4 = sub >> 2, jj = (sub & 3) + 4 * odd;
    #pragma unroll
    for (int h = 0; h < NHD; ++h) {
      skA[(kt * NHD + h) * 16 + kap] =
          make_uint4(bf16rne(kk[h*3]) | (bf16rne(kk[h*3+1]) << 16), bf16rne(kk[h*3+2]), 0u, 0u);
      sqQ[(kt * NHD + h) * 16 + kap] =
          make_uint4(bf16rne(qq[h*3]) | (bf16rne(qq[h*3+1]) << 16), bf16rne(qq[h*3+2]), 0u, 0u);
      #pragma unroll
      for (int n = 0; n < 4; ++n) {
        float vval = (n < 3) ? vv[h*3+n] : 1.0f;   // ones column -> denom
        svB[(((grp * NHD + h) * 4 + q4) * 4 + n) * 8 + jj] = (unsigned short)bf16rne(vval);
      }
    }
  }
  __syncthreads();

  const int lane = t & 63, wv = t >> 6;
  const int lq = lane >> 4, ln = lane & 15;

  // ---- Qᵀ fragments for this wave's 4 row-tiles (quads >= 1 zeroed) ----
  short8v qf[4][NHD];
  #pragma unroll
  for (int i = 0; i < 4; ++i)
    #pragma unroll
    for (int h = 0; h < NHD; ++h) {
      U16 u; u.u = sqQ[((wv * 4 + i) * NHD + h) * 16 + ln];
      if (lq != 0) u.u = make_uint4(0u, 0u, 0u, 0u);
      qf[i][h] = u.s;
    }

  floatx4 oacc[4][NHD];
  #pragma unroll
  for (int i = 0; i < 4; ++i)
    #pragma unroll
    for (int h = 0; h < NHD; ++h) {
      floatx4 z = {0.f, 0.f, 0.f, 0.f};
      oacc[i][h] = z;
    }

  const uint4* svB4 = (const uint4*)svB;
  for (int kg = 0; kg < 16; ++kg) {
    #pragma unroll
    for (int h = 0; h < NHD; ++h) {
      U16 ke, ko, vf;
      ke.u = skA[((2 * kg + 0) * NHD + h) * 16 + ln];            // even key-tile (bcast x4)
      ko.u = skA[((2 * kg + 1) * NHD + h) * 16 + ln];            // odd key-tile
      vf.u = svB4[((kg * NHD + h) * 4 + lq) * 4 + (ln & 3)];     // V' frag (permuted order)
      #pragma unroll
      for (int i = 0; i < 4; ++i) {
        floatx4 zc = {0.f, 0.f, 0.f, 0.f};
        floatx4 se = __builtin_amdgcn_mfma_f32_16x16x32_bf16(ke.s, qf[i][h], zc, 0, 0, 0);
        floatx4 so = __builtin_amdgcn_mfma_f32_16x16x32_bf16(ko.s, qf[i][h], zc, 0, 0, 0);
        // hazard-aware compiler intrinsic: bare v_exp_f32, no libcall, no asm opacity
        unsigned p0 = __float_as_uint(__builtin_amdgcn_exp2f(se[0]));
        unsigned p1 = __float_as_uint(__builtin_amdgcn_exp2f(se[1]));
        unsigned p2 = __float_as_uint(__builtin_amdgcn_exp2f(se[2]));
        unsigned p3 = __float_as_uint(__builtin_amdgcn_exp2f(se[3]));
        unsigned p4 = __float_as_uint(__builtin_amdgcn_exp2f(so[0]));
        unsigned p5 = __float_as_uint(__builtin_amdgcn_exp2f(so[1]));
        unsigned p6 = __float_as_uint(__builtin_amdgcn_exp2f(so[2]));
        unsigned p7 = __float_as_uint(__builtin_amdgcn_exp2f(so[3]));
        U16 pf;   // one v_perm each: low short = bf16(first), high short = bf16(second)
        pf.u.x = __builtin_amdgcn_perm(p1, p0, 0x07060302u);  // slots j=0,1
        pf.u.y = __builtin_amdgcn_perm(p3, p2, 0x07060302u);  // slots j=2,3
        pf.u.z = __builtin_amdgcn_perm(p5, p4, 0x07060302u);  // slots j=4,5
        pf.u.w = __builtin_amdgcn_perm(p7, p6, 0x07060302u);  // slots j=6,7
        oacc[i][h] = __builtin_amdgcn_mfma_f32_16x16x32_bf16(pf.s, vf.s, oacc[i][h], 0, 0, 0);
      }
    }
  }

  // ---- redistribute O (C-layout, cols 0..3 valid) to per-row layout in LDS ----
  if (ln < 4) {
    #pragma unroll
    for (int i = 0; i < 4; ++i)
      #pragma unroll
      for (int h = 0; h < NHD; ++h)
        #pragma unroll
        for (int r = 0; r < 4; ++r)
          sO[((wv * 4 + i) * 16 + lq * 4 + r) * 16 + h * 4 + ln] = oacc[i][h][r];
  }
  __syncthreads();

  // ---- normalize + out-projection for this thread's row ----
  {
    const float4* sr = (const float4*)(sO + t * 16);
    float o[EMB];
    #pragma unroll
    for (int h = 0; h < NHD; ++h) {
      float4 Oh = sr[h];
      float inv = 1.0f / fmaxf(Oh.w, 1e-20f);   // inert guard
      o[h*3+0] = Oh.x * inv; o[h*3+1] = Oh.y * inv; o[h*3+2] = Oh.z * inv;
    }
    #pragma unroll
    for (int e = 0; e < EMB; ++e) {
      float s = b_out[e];
      #pragma unroll
      for (int f = 0; f < EMB; ++f) s = fmaf(o[f], w_out[e * EMB + f], s);
      outv[e] = s;
    }
  }
}

__global__ __launch_bounds__(512, 2)
void pcr_kernel(const float* __restrict__ x_orig, const float* __restrict__ y_orig,
                const float* __restrict__ lin_in_w,  const float* __restrict__ lin_in_b,
                const float* __restrict__ lin_in2_w, const float* __restrict__ lin_in2_b,
                const float* __restrict__ attn_in_w,  const float* __restrict__ attn_in_b,
                const float* __restrict__ attn_out_w, const float* __restrict__ attn_out_b,
                const float* __restrict__ attn2_in_w,  const float* __restrict__ attn2_in_b,
                const float* __restrict__ attn2_out_w, const float* __restrict__ attn2_out_b,
                const float* __restrict__ cross_in_w,  const float* __restrict__ cross_in_b,
                const float* __restrict__ cross_out_w, const float* __restrict__ cross_out_b,
                const float* __restrict__ lin_out_w, const float* __restrict__ lin_out_b,
                float* __restrict__ out)
{
  __shared__ __align__(16) uint4 skA[32 * NHD * 16];                   // 32 KB [kt][h][key]
  __shared__ __align__(16) uint4 sqQ[32 * NHD * 16];                   // 32 KB [rt][h][row]
  __shared__ __align__(16) unsigned short svB[16 * NHD * 4 * 4 * 8];   // 16 KB [kg][h][lq][n][j]
  __shared__ __align__(16) float sO[PTS * 16];                         // 32 KB
  __shared__ float sred[8 * 12];

  const int b = blockIdx.x;
  const int t = threadIdx.x;
  const int base = (b * PTS + t) * 3;

  // ---- center x and y (per-batch mean over points) ----
  float x3[3], y3[3], ymean[3];
  {
    float r6[6];
    #pragma unroll
    for (int i = 0; i < 3; ++i) r6[i]     = x_orig[base + i];
    #pragma unroll
    for (int i = 0; i < 3; ++i) r6[3 + i] = y_orig[base + i];
    float xl[3] = {r6[0], r6[1], r6[2]};
    float yl[3] = {r6[3], r6[4], r6[5]};
    block_reduce<6>(r6, sred, t);
    #pragma unroll
    for (int i = 0; i < 3; ++i) {
      x3[i]    = xl[i] - r6[i] * (1.f / PTS);
      ymean[i] = r6[3 + i] * (1.f / PTS);
      y3[i]    = yl[i] - ymean[i];
    }
  }

  // ---- input linears (3 -> 12) ----
  float xi[EMB], yi[EMB];
  #pragma unroll
  for (int e = 0; e < EMB; ++e) {
    float sx = lin_in_b[e], sy = lin_in2_b[e];
    #pragma unroll
    for (int i = 0; i < 3; ++i) {
      sx = fmaf(x3[i], lin_in_w[e * 3 + i], sx);
      sy = fmaf(y3[i], lin_in2_w[e * 3 + i], sy);
    }
    xi[e] = sx; yi[e] = sy;
  }

  // ---- three attention layers (MFMA) ----
  float tmp[EMB];
  mha_mfma(xi, xi, attn_in_w,  attn_in_b,  attn_out_w,  attn_out_b,  tmp, skA, sqQ, svB, sO, t);
  #pragma unroll
  for (int e = 0; e < EMB; ++e) xi[e] = tmp[e];
  mha_mfma(yi, yi, attn2_in_w, attn2_in_b, attn2_out_w, attn2_out_b, tmp, skA, sqQ, svB, sO, t);
  #pragma unroll
  for (int e = 0; e < EMB; ++e) yi[e] = tmp[e];
  mha_mfma(xi, yi, cross_in_w, cross_in_b, cross_out_w, cross_out_b, tmp, skA, sqQ, svB, sO, t);

  // ---- output linear (12 -> 3); bp = coords + x ----
  float bp[3];
  #pragma unroll
  for (int d = 0; d < 3; ++d) {
    float c = lin_out_b[d];
    #pragma unroll
    for (int e = 0; e < EMB; ++e) c = fmaf(tmp[e], lin_out_w[d * EMB + e], c);
    bp[d] = c + x3[d];
  }

  // ---- Kabsch: H[i][j] = sum_p x[p,i]*bp[p,j] (sum_p x = 0), plus sum bp ----
  float r12[12];
  #pragma unroll
  for (int i = 0; i < 3; ++i)
    #pragma unroll
    for (int j = 0; j < 3; ++j) r12[i * 3 + j] = x3[i] * bp[j];
  #pragma unroll
  for (int j = 0; j < 3; ++j) r12[9 + j] = bp[j];
  block_reduce<12>(r12, sred, t);

  float cA[3];
  #pragma unroll
  for (int j = 0; j < 3; ++j) cA[j] = r12[9 + j] * (1.f / PTS);

  // ---- R = polar factor of H via determinant-scaled Newton (== U @ Vt) ----
  float a00 = r12[0], a01 = r12[1], a02 = r12[2];
  float a10 = r12[3], a11 = r12[4], a12_ = r12[5];
  float a20 = r12[6], a21 = r12[7], a22 = r12[8];

  float c0 = fabsf(a00) + fabsf(a10) + fabsf(a20);
  float c1 = fabsf(a01) + fabsf(a11) + fabsf(a21);
  float c2 = fabsf(a02) + fabsf(a12_) + fabsf(a22);
  float r0 = fabsf(a00) + fabsf(a01) + fabsf(a02);
  float r1 = fabsf(a10) + fabsf(a11) + fabsf(a12_);
  float r2 = fabsf(a20) + fabsf(a21) + fabsf(a22);
  float fsc = rsqrtf(fmaxf(c0, fmaxf(c1, c2)) * fmaxf(r0, fmaxf(r1, r2)) + 1e-30f);
  a00 *= fsc; a01 *= fsc; a02 *= fsc;
  a10 *= fsc; a11 *= fsc; a12_ *= fsc;
  a20 *= fsc; a21 *= fsc; a22 *= fsc;

  #pragma unroll 1
  for (int it = 0; it < 12; ++it) {
    float C00 = a11*a22 - a12_*a21;
    float C01 = a12_*a20 - a10*a22;
    float C02 = a10*a21 - a11*a20;
    float C10 = a02*a21 - a01*a22;
    float C11 = a00*a22 - a02*a20;
    float C12 = a01*a20 - a00*a21;
    float C20 = a01*a12_ - a02*a11;
    float C21 = a02*a10 - a00*a12_;
    float C22 = a00*a11 - a01*a10;
    float det = a00*C00 + a01*C01 + a02*C02;
    float g  = 1.0f / cbrtf(fabsf(det) + 1e-30f);
    float dg = det * g;
    dg = copysignf(fmaxf(fabsf(dg), 1e-25f), dg);   // inert guard
    float id = 0.5f / dg;
    float gh = 0.5f * g;
    a00 = gh*a00 + C00*id; a01 = gh*a01 + C01*id; a02 = gh*a02 + C02*id;
    a10 = gh*a10 + C10*id; a11 = gh*a11 + C11*id; a12_ = gh*a12_ + C12*id;
    a20 = gh*a20 + C20*id; a21 = gh*a21 + C21*id; a22 = gh*a22 + C22*id;
  }

  // ---- out = x @ R + t + y_translate ----
  float o0 = fmaf(x3[0], a00, fmaf(x3[1], a10, fmaf(x3[2], a20, cA[0] + ymean[0])));
  float o1 = fmaf(x3[0], a01, fmaf(x3[1], a11, fmaf(x3[2], a21, cA[1] + ymean[1])));
  float o2 = fmaf(x3[0], a02, fmaf(x3[1], a12_, fmaf(x3[2], a22, cA[2] + ymean[2])));
  out[base + 0] = o0;
  out[base + 1] = o1;
  out[base + 2] = o2;
}

extern "C" void kernel_launch(void* const* d_in, const int* in_sizes, int n_in,
                              void* d_out, int out_size, void* d_ws, size_t ws_size,
                              hipStream_t stream) {
  const float* p[20];
  for (int i = 0; i < 20; ++i) p[i] = (const float*)d_in[i];
  pcr_kernel<<<dim3(NB), dim3(512), 0, stream>>>(
      p[0], p[1], p[2], p[3], p[4], p[5], p[6], p[7], p[8], p[9],
      p[10], p[11], p[12], p[13], p[14], p[15], p[16], p[17], p[18], p[19],
      (float*)d_out);
}